// Round 1
// baseline (220.199 us; speedup 1.0000x reference)
//
#include <hip/hip_runtime.h>

// Problem: 8 x 1 x 512 x 512 f32 image, 17x17 windows @ stride 4 -> 124x124 windows/batch.
// Per window: stats (mean/std/max/min), 4-bin value histogram, 12-offset GLCM features.
// Output: mean over windows -> (8, 68) f32.
//
// Channel map: 0-3 stats, 4-7 hist, 8-19 contrast, 20-31 homogeneity, 32-43 energy,
//              44-55 correlation, 56-67 entropy. Offsets k: (0,1),(1,1),(1,0),(1,-1),
//              (0,2),(1,1),(2,0),(1,-1),(0,4),(3,3),(4,0),(3,-3). k=5 dup of k=1, k=7 dup of k=3.

#define G_MEAN_F 85.384f
#define G_STD_F  53.798f

// 15 unordered (lo<=hi) level pairs for LEV=5
__device__ constexpr int LO15[15] = {0,0,0,0,0,1,1,1,1,2,2,2,3,3,4};
__device__ constexpr int HI15[15] = {0,1,2,3,4,1,2,3,4,2,3,4,3,4,4};

__device__ __forceinline__ float wred(float v) {
#pragma unroll
  for (int m = 32; m; m >>= 1) v += __shfl_xor(v, m, 64);
  return v;
}

// One GLCM offset (DR,DC) for this thread's window.
// qwin: byte ptr to window origin in qtile (row stride 52 bytes).
// slot: this thread's private histogram column (hist + (tid>>1)); two threads share a
//       u32 via 16-bit halves selected by inc/shft. Bin u lives at slot[(lo*5+hi)*64].
template<int DR, int DC>
__device__ __forceinline__ void glcm_offset(const unsigned char* qwin,
                                            unsigned* slot, unsigned inc, int shft,
                                            bool valid, float* outb, int k0, int k1)
{
  constexpr int ADC = DC < 0 ? -DC : DC;
  constexpr int W = 17 - ADC;   // pairs per row
  constexpr int R = 17 - DR;    // row iterations
  constexpr int AO = DC < 0 ? ADC : 0;  // a column offset
  constexpr int BO = DC > 0 ? DC : 0;   // b column offset

  // zero my 15 bins (paired lanes write the same 0 word: benign)
#pragma unroll
  for (int u = 0; u < 15; ++u) slot[(LO15[u] * 5 + HI15[u]) * 64] = 0u;

#pragma unroll 1
  for (int r = 0; r < R; ++r) {
    const unsigned* pa = (const unsigned*)(qwin + r * 52);
    unsigned a0 = pa[0], a1 = pa[1], a2 = pa[2], a3 = pa[3], a4 = pa[4];
    unsigned b0, b1, b2, b3, b4;
    if (DR > 0) {
      const unsigned* pb = (const unsigned*)(qwin + (r + DR) * 52);
      b0 = pb[0]; b1 = pb[1]; b2 = pb[2]; b3 = pb[3]; b4 = pb[4];
    } else {
      b0 = a0; b1 = a1; b2 = a2; b3 = a3; b4 = a4;
    }
    const unsigned aw[5] = {a0, a1, a2, a3, a4};
    const unsigned bw[5] = {b0, b1, b2, b3, b4};
#pragma unroll
    for (int c = 0; c < W; ++c) {
      const int ca = c + AO, cb = c + BO;   // compile-time after unroll
      unsigned va = (aw[ca >> 2] >> ((ca & 3) * 8)) & 0xffu;
      unsigned vb = (bw[cb >> 2] >> ((cb & 3) * 8)) & 0xffu;
      unsigned lo = min(va, vb), hi = max(va, vb);
      atomicAdd(slot + (lo * 5u + hi) * 64u, inc);  // ds_add_u32, no return -> no stall
    }
  }

  // ---- readback (same-wave DS ops are in order) + features ----
  constexpr float Np = (float)(R * W);
  const float invN = 1.0f / Np;
  const float inv2N = 0.5f / Np;
  float mv[15];
#pragma unroll
  for (int u = 0; u < 15; ++u)
    mv[u] = (float)((slot[(LO15[u] * 5 + HI15[u]) * 64] >> shft) & 0xffffu);

  float con = 0.0f, hom = 0.0f, eac = 0.0f, ent = 0.0f;
  float P[5] = {0, 0, 0, 0, 0};
#pragma unroll
  for (int u = 0; u < 15; ++u) {
    const int lo = LO15[u], hi = HI15[u];
    const float m = mv[u];
    const float d2 = (float)((hi - lo) * (hi - lo));
    con += m * d2;
    hom += m * (1.0f / (1.0f + d2));
    if (lo == hi) {
      eac += m * m;
      P[lo] += 2.0f * m;
      float g = m * invN;                 // diagonal entry of normalized symmetric G
      ent -= g * __log2f(g + 1e-8f);
    } else {
      eac += 0.5f * m * m;                // two entries of (m/(2N))^2
      P[lo] += m; P[hi] += m;
      float g = m * inv2N;
      ent -= 2.0f * g * __log2f(g + 1e-8f);
    }
  }
  con *= invN;
  hom *= invN;
  float ene = sqrtf(eac) * invN;

  float mu = 0.0f;
#pragma unroll
  for (int i = 0; i < 5; ++i) { P[i] *= inv2N; mu += (float)i * P[i]; }
  float s2 = 0.0f;
#pragma unroll
  for (int i = 0; i < 5; ++i) { float d = (float)i - mu; s2 = fmaf(P[i] * d, d, s2); }
  float sd = sqrtf(s2);
  float denom = sd * sd;                  // ref does std_i*std_j with std_i==std_j
  float cov = 0.0f;
#pragma unroll
  for (int u = 0; u < 15; ++u)
    cov += (mv[u] * invN) * ((float)LO15[u] - mu) * ((float)HI15[u] - mu);
  float corr = (denom < 1e-15f) ? 1.0f : cov / fmaxf(denom, 1e-30f);

  if (!valid) { con = 0; hom = 0; ene = 0; corr = 0; ent = 0; }
  con = wred(con); hom = wred(hom); ene = wred(ene); corr = wred(corr); ent = wred(ent);
  if ((threadIdx.x & 63) == 0) {
    const float s = 1.0f / 15376.0f;      // 1/(124*124): block partials sum to the mean
    unsafeAtomicAdd(outb + 8 + k0, con * s);
    unsafeAtomicAdd(outb + 20 + k0, hom * s);
    unsafeAtomicAdd(outb + 32 + k0, ene * s);
    unsafeAtomicAdd(outb + 44 + k0, corr * s);
    unsafeAtomicAdd(outb + 56 + k0, ent * s);
    if (k1 >= 0) {                        // duplicated offset -> identical features
      unsafeAtomicAdd(outb + 8 + k1, con * s);
      unsafeAtomicAdd(outb + 20 + k1, hom * s);
      unsafeAtomicAdd(outb + 32 + k1, ene * s);
      unsafeAtomicAdd(outb + 44 + k1, corr * s);
      unsafeAtomicAdd(outb + 56 + k1, ent * s);
    }
  }
}

// Block = 128 threads = 2 waves, covering an 8x8 window tile (each wave handles all 64
// windows; wave0: stats+hist+5 offsets, wave1: other 5 offsets). Tile pixels: 45x45.
// LDS row stride 52 bytes: odd word count -> conflict-free row loads; 16B-aligned f32 rows.
__global__ __launch_bounds__(128)
void glcm_feat_kernel(const float* __restrict__ x, float* __restrict__ out)
{
  __shared__ __align__(16) float ftile[45 * 52];         // 9360 B
  __shared__ __align__(4) unsigned char qtile[45 * 52 + 4]; // 2344 B
  __shared__ unsigned hist[25 * 64];                     // 6400 B (16-bit halves, 128 thr)

  const int tid = threadIdx.x;
  const int b = blockIdx.z;
  const int px0 = blockIdx.y * 32;   // pixel row origin (window-tile * 8 windows * stride 4)
  const int py0 = blockIdx.x * 32;   // pixel col origin
  const float* xb = x + (size_t)b * 512 * 512;

  const float T1 = 0.5f;
  const float T2 = (float)(85.384 - 53.798);
  const float T3 = 85.384f;
  const float T4 = (float)(85.384 + 53.798);

  // cooperative tile load + quantize (digitize-1 = #(bins<=x)-1; x>=0 term always 1)
#pragma unroll 1
  for (int i = tid; i < 45 * 52; i += 128) {
    int row = i / 52;
    int col = i - row * 52;
    float xv = 0.0f;
    int gr = px0 + row, gc = py0 + col;
    if (col < 45 && gr < 512 && gc < 512) xv = xb[gr * 512 + gc];
    ftile[i] = xv;
    int q = (int)(xv >= T1) + (int)(xv >= T2) + (int)(xv >= T3) + (int)(xv >= T4);
    qtile[i] = (unsigned char)q;
  }
  __syncthreads();

  const int lane = tid & 63;
  const int lx = lane >> 3, ly = lane & 7;     // window coords within 8x8 tile
  const int wx = blockIdx.y * 8 + lx;
  const int wy = blockIdx.x * 8 + ly;
  const bool valid = (wx < 124) && (wy < 124);
  const unsigned char* qwin = qtile + (lx * 4) * 52 + ly * 4;
  const float* fwin = ftile + (lx * 4) * 52 + ly * 4;
  unsigned* slot = hist + (tid >> 1);
  const unsigned inc = 1u << ((tid & 1) * 16);
  const int shft = (tid & 1) * 16;
  float* outb = out + b * 68;

  if (tid < 64) {
    // ---- stats + value histogram ----
    float sum = 0.0f, ssq = 0.0f, mx = -1e30f, mn = 1e30f;
    int c05 = 0, c31 = 0, c85 = 0, c139 = 0;
#pragma unroll 1
    for (int r = 0; r < 17; ++r) {
      const float* pf = fwin + r * 52;
#pragma unroll
      for (int j = 0; j < 17; ++j) {
        float xv = pf[j];
        sum += xv;
        ssq = fmaf(xv, xv, ssq);
        mx = fmaxf(mx, xv);
        mn = fminf(mn, xv);
        c05 += (xv >= T1); c31 += (xv >= T2); c85 += (xv >= T3); c139 += (xv >= T4);
      }
    }
    float mean = sum * (1.0f / 289.0f);
    float var = fmaxf(ssq * (1.0f / 289.0f) - mean * mean, 0.0f);
    float fm = mean / G_MEAN_F;
    float fs = sqrtf(var) / G_STD_F;
    float fmx = (mx - fm) / G_STD_F;   // ref subtracts the *normalized* mean
    float fmn = (fm - mn) / G_STD_F;
    int n1 = c05 - c31, n2 = c31 - c85, n3 = c85 - c139, n4 = c139;
    float ti = (c05 > 0) ? 1.0f / (float)c05 : 0.0f;
    float h1 = n1 * ti, h2 = n2 * ti, h3 = n3 * ti, h4 = n4 * ti;
    if (!valid) { fm = fs = fmx = fmn = h1 = h2 = h3 = h4 = 0.0f; }
    fm = wred(fm); fs = wred(fs); fmx = wred(fmx); fmn = wred(fmn);
    h1 = wred(h1); h2 = wred(h2); h3 = wred(h3); h4 = wred(h4);
    if (lane == 0) {
      const float s = 1.0f / 15376.0f;
      unsafeAtomicAdd(outb + 0, fm * s);
      unsafeAtomicAdd(outb + 1, fs * s);
      unsafeAtomicAdd(outb + 2, fmx * s);
      unsafeAtomicAdd(outb + 3, fmn * s);
      unsafeAtomicAdd(outb + 4, h1 * s);
      unsafeAtomicAdd(outb + 5, h2 * s);
      unsafeAtomicAdd(outb + 6, h3 * s);
      unsafeAtomicAdd(outb + 7, h4 * s);
    }
    glcm_offset<0, 1>(qwin, slot, inc, shft, valid, outb, 0, -1);
    glcm_offset<1, -1>(qwin, slot, inc, shft, valid, outb, 3, 7);
    glcm_offset<0, 2>(qwin, slot, inc, shft, valid, outb, 4, -1);
    glcm_offset<3, 3>(qwin, slot, inc, shft, valid, outb, 9, -1);
    glcm_offset<0, 4>(qwin, slot, inc, shft, valid, outb, 8, -1);
  } else {
    glcm_offset<1, 1>(qwin, slot, inc, shft, valid, outb, 1, 5);
    glcm_offset<1, 0>(qwin, slot, inc, shft, valid, outb, 2, -1);
    glcm_offset<2, 0>(qwin, slot, inc, shft, valid, outb, 6, -1);
    glcm_offset<4, 0>(qwin, slot, inc, shft, valid, outb, 10, -1);
    glcm_offset<3, -3>(qwin, slot, inc, shft, valid, outb, 11, -1);
  }
}

extern "C" void kernel_launch(void* const* d_in, const int* in_sizes, int n_in,
                              void* d_out, int out_size, void* d_ws, size_t ws_size,
                              hipStream_t stream)
{
  const float* x = (const float*)d_in[0];
  float* out = (float*)d_out;
  // d_out is re-poisoned before every launch; we accumulate with atomics -> zero it first.
  hipMemsetAsync(out, 0, (size_t)out_size * sizeof(float), stream);
  dim3 grid(16, 16, 8);   // x: wy tiles, y: wx tiles, z: batch
  dim3 block(128);
  glcm_feat_kernel<<<grid, block, 0, stream>>>(x, out);
}

// Round 2
// 217.993 us; speedup vs baseline: 1.0101x; 1.0101x over previous
//
#include <hip/hip_runtime.h>

// 8 x 512 x 512 f32 -> 17x17 windows @ stride 4 -> 124x124 windows/batch -> (8,68) means.
// Bitplane GLCM: per-(tile-row, level) bitmasks built by wave ballot; each lane holds its
// window's 17-bit row masks and computes co-occurrence counts with AND+POPCNT in registers.
// No LDS histogram, no DS atomics. Offsets (dup k5=(1,1), k7=(1,-1) share compute):
//   wave0: (0,1)k0 (0,2)k4 (0,4)k8 [one DR=0 pass] + (3,3)k9 + (2,0)k6 + stats/hist
//   wave1: (1,1)k1,k5 (1,0)k2 [one DR=1 pass] + (1,-1)k3,k7 + (4,0)k10 + (3,-3)k11

#define G_MEAN_F 85.384f
#define G_STD_F  53.798f

__device__ constexpr int LO15[15] = {0,0,0,0,0,1,1,1,1,2,2,2,3,3,4};
__device__ constexpr int HI15[15] = {0,1,2,3,4,1,2,3,4,2,3,4,3,4,4};

__device__ __forceinline__ float wred(float v) {
#pragma unroll
  for (int m = 32; m; m >>= 1) v += __shfl_xor(v, m, 64);
  return v;
}

// Read one tile row's 4 level-masks (u64) from LDS, slice this window's 17 bits.
__device__ __forceinline__ void load_row(const unsigned long long* mrow, int ly4, unsigned m[5]) {
  unsigned long long a = mrow[0], b = mrow[1], c = mrow[2], d = mrow[3];
  m[1] = (unsigned)(a >> ly4) & 0x1FFFFu;
  m[2] = (unsigned)(b >> ly4) & 0x1FFFFu;
  m[3] = (unsigned)(c >> ly4) & 0x1FFFFu;
  m[4] = (unsigned)(d >> ly4) & 0x1FFFFu;
  m[0] = 0x1FFFFu & ~(m[1] | m[2] | m[3] | m[4]);
}

// Unordered-bin co-occurrence update: cnt[u] += popc(a_i & b_j) (+ popc(a_j & b_i) off-diag).
__device__ __forceinline__ void upd(unsigned cnt[15], const unsigned a[5], const unsigned b[5]) {
#pragma unroll
  for (int u = 0; u < 15; ++u) {
    const int i = LO15[u], j = HI15[u];
    unsigned s = __popc(a[i] & b[j]);
    if (i != j) s += __popc(a[j] & b[i]);
    cnt[u] += s;
  }
}

// GLCM feature epilogue (verified in R1): cnt[u] = symmetric-unordered pair counts.
__device__ __forceinline__ void emit(const unsigned cnt[15], float Np, bool valid,
                                     float* outb, int k0, int k1) {
  const float invN = 1.0f / Np;
  const float inv2N = 0.5f / Np;
  float con = 0.0f, hom = 0.0f, eac = 0.0f, ent = 0.0f;
  float P[5] = {0, 0, 0, 0, 0};
#pragma unroll
  for (int u = 0; u < 15; ++u) {
    const int lo = LO15[u], hi = HI15[u];
    const float m = (float)cnt[u];
    const float d2 = (float)((hi - lo) * (hi - lo));
    con += m * d2;
    hom += m * (1.0f / (1.0f + d2));
    if (lo == hi) {
      eac += m * m;
      P[lo] += 2.0f * m;
      float g = m * invN;
      ent -= g * __log2f(g + 1e-8f);
    } else {
      eac += 0.5f * m * m;
      P[lo] += m; P[hi] += m;
      float g = m * inv2N;
      ent -= 2.0f * g * __log2f(g + 1e-8f);
    }
  }
  con *= invN;
  hom *= invN;
  float ene = sqrtf(eac) * invN;
  float mu = 0.0f;
#pragma unroll
  for (int i = 0; i < 5; ++i) { P[i] *= inv2N; mu += (float)i * P[i]; }
  float s2 = 0.0f;
#pragma unroll
  for (int i = 0; i < 5; ++i) { float d = (float)i - mu; s2 = fmaf(P[i] * d, d, s2); }
  float sd = sqrtf(s2);
  float denom = sd * sd;
  float cov = 0.0f;
#pragma unroll
  for (int u = 0; u < 15; ++u)
    cov += ((float)cnt[u] * invN) * ((float)LO15[u] - mu) * ((float)HI15[u] - mu);
  float corr = (denom < 1e-15f) ? 1.0f : cov / fmaxf(denom, 1e-30f);

  if (!valid) { con = 0; hom = 0; ene = 0; corr = 0; ent = 0; }
  con = wred(con); hom = wred(hom); ene = wred(ene); corr = wred(corr); ent = wred(ent);
  if ((threadIdx.x & 63) == 0) {
    const float s = 1.0f / 15376.0f;
    unsafeAtomicAdd(outb + 8 + k0, con * s);
    unsafeAtomicAdd(outb + 20 + k0, hom * s);
    unsafeAtomicAdd(outb + 32 + k0, ene * s);
    unsafeAtomicAdd(outb + 44 + k0, corr * s);
    unsafeAtomicAdd(outb + 56 + k0, ent * s);
    if (k1 >= 0) {
      unsafeAtomicAdd(outb + 8 + k1, con * s);
      unsafeAtomicAdd(outb + 20 + k1, hom * s);
      unsafeAtomicAdd(outb + 32 + k1, ene * s);
      unsafeAtomicAdd(outb + 44 + k1, corr * s);
      unsafeAtomicAdd(outb + 56 + k1, ent * s);
    }
  }
}

// DR=0 offsets (0,1),(0,2),(0,4) in one row pass; also accumulates level counts nv[1..4].
__device__ __forceinline__ void glcm_dr0_trio(const unsigned long long* mbase, int ly4,
                                              bool valid, float* outb, unsigned nv[4]) {
  unsigned c1[15], c2[15], c4[15];
#pragma unroll
  for (int u = 0; u < 15; ++u) { c1[u] = 0; c2[u] = 0; c4[u] = 0; }
  nv[0] = nv[1] = nv[2] = nv[3] = 0;
#pragma unroll 1
  for (int r = 0; r < 17; ++r) {
    unsigned m[5];
    load_row(mbase + r * 5, ly4, m);
    nv[0] += __popc(m[1]); nv[1] += __popc(m[2]);
    nv[2] += __popc(m[3]); nv[3] += __popc(m[4]);
    unsigned s1[5], s2[5], s4[5];
#pragma unroll
    for (int v = 0; v < 5; ++v) { s1[v] = m[v] >> 1; s2[v] = m[v] >> 2; s4[v] = m[v] >> 4; }
    upd(c1, m, s1);
    upd(c2, m, s2);
    upd(c4, m, s4);
  }
  emit(c1, 272.0f, valid, outb, 0, -1);
  emit(c2, 255.0f, valid, outb, 4, -1);
  emit(c4, 221.0f, valid, outb, 8, -1);
}

// DR=1 offsets (1,1) and (1,0) in one rolling pass.
__device__ __forceinline__ void glcm_dr1_pair(const unsigned long long* mbase, int ly4,
                                              bool valid, float* outb) {
  unsigned ca[15], cb[15];
#pragma unroll
  for (int u = 0; u < 15; ++u) { ca[u] = 0; cb[u] = 0; }
  unsigned p[5], c[5];
  load_row(mbase, ly4, p);
#pragma unroll 1
  for (int r = 1; r < 17; ++r) {
    load_row(mbase + r * 5, ly4, c);
    unsigned s[5];
#pragma unroll
    for (int v = 0; v < 5; ++v) s[v] = c[v] >> 1;
    upd(ca, p, s);   // (1,1)
    upd(cb, p, c);   // (1,0)
#pragma unroll
    for (int v = 0; v < 5; ++v) p[v] = c[v];
  }
  emit(ca, 256.0f, valid, outb, 1, 5);
  emit(cb, 272.0f, valid, outb, 2, -1);
}

// Generic single offset, rolling DR+1 row-mask window. DC<0 shifts the A (upper) row.
template<int DR, int DC>
__device__ __forceinline__ void glcm_one(const unsigned long long* mbase, int ly4,
                                         float Np, bool valid, float* outb, int k0, int k1) {
  unsigned cnt[15];
#pragma unroll
  for (int u = 0; u < 15; ++u) cnt[u] = 0;
  unsigned buf[DR + 1][5];
#pragma unroll
  for (int r = 0; r < DR; ++r) load_row(mbase + r * 5, ly4, buf[r]);
#pragma unroll 1
  for (int r = DR; r < 17; ++r) {
    load_row(mbase + r * 5, ly4, buf[DR]);
    unsigned as[5], bs[5];
#pragma unroll
    for (int v = 0; v < 5; ++v) {
      as[v] = (DC < 0) ? (buf[0][v] >> (-DC)) : buf[0][v];
      bs[v] = (DC > 0) ? (buf[DR][v] >> DC) : buf[DR][v];
    }
    upd(cnt, as, bs);
#pragma unroll
    for (int i = 0; i < DR; ++i)
#pragma unroll
      for (int v = 0; v < 5; ++v) buf[i][v] = buf[i + 1][v];
  }
  emit(cnt, Np, valid, outb, k0, k1);
}

__global__ __launch_bounds__(128)
void glcm_feat_kernel(const float* __restrict__ x, float* __restrict__ out) {
  __shared__ unsigned long long masks[45 * 5];  // [tile_row][level-1], slot 4 = pad (1800 B)

  const int tid = threadIdx.x;
  const int lane = tid & 63;
  const int wid = tid >> 6;
  const int b = blockIdx.z;
  const int px0 = blockIdx.y * 32;
  const int py0 = blockIdx.x * 32;
  const float* xb = x + (size_t)b * 512 * 512;

  const float T1 = 0.5f;
  const float T2 = (float)(85.384 - 53.798);
  const float T3 = 85.384f;
  const float T4 = (float)(85.384 + 53.798);

  // Phase A: build per-row level bitmasks via ballot (lane c = tile column c).
#pragma unroll 1
  for (int row = wid; row < 45; row += 2) {
    int gr = px0 + row; if (gr > 511) gr = 511;
    int gc = py0 + lane;
    float xv = 0.0f;
    if (lane < 45 && gc < 512) xv = xb[gr * 512 + gc];
    int q = (int)(xv >= T1) + (int)(xv >= T2) + (int)(xv >= T3) + (int)(xv >= T4);
    unsigned long long b1 = __ballot(q == 1);
    unsigned long long b2 = __ballot(q == 2);
    unsigned long long b3 = __ballot(q == 3);
    unsigned long long b4 = __ballot(q == 4);
    unsigned long long bv = b4;
    if (lane == 1) bv = b1; else if (lane == 2) bv = b2; else if (lane == 3) bv = b3;
    if (lane >= 1 && lane <= 4) masks[row * 5 + (lane - 1)] = bv;
  }
  __syncthreads();

  // Phase B: one window per lane (8x8 window tile), offsets split across the two waves.
  const int lx = lane >> 3, ly = lane & 7;
  const int wx = blockIdx.y * 8 + lx;
  const int wy = blockIdx.x * 8 + ly;
  const bool valid = (wx < 124) && (wy < 124);
  const unsigned long long* mbase = masks + (lx * 4) * 5;
  const int ly4 = ly * 4;
  float* outb = out + b * 68;

  if (wid == 0) {
    unsigned nv[4];
    glcm_dr0_trio(mbase, ly4, valid, outb, nv);
    glcm_one<3, 3>(mbase, ly4, 196.0f, valid, outb, 9, -1);
    glcm_one<2, 0>(mbase, ly4, 255.0f, valid, outb, 6, -1);

    // value histogram from level counts
    unsigned tot = nv[0] + nv[1] + nv[2] + nv[3];
    float ti = (tot > 0) ? 1.0f / (float)tot : 0.0f;
    float h1 = (float)nv[0] * ti, h2 = (float)nv[1] * ti;
    float h3 = (float)nv[2] * ti, h4 = (float)nv[3] * ti;

    // float stats straight from global (tile is L1/L2 resident); clamp keeps invalid
    // lanes in-bounds & 16B-aligned (their results are zeroed by `valid`).
    int r0 = px0 + lx * 4; if (r0 > 495) r0 = 495;
    int c0 = py0 + ly * 4; if (c0 > 492) c0 = 492;
    const float* fw = xb + (size_t)r0 * 512 + c0;
    float sum = 0.0f, ssq = 0.0f, mx = -1e30f, mn = 1e30f;
#pragma unroll 1
    for (int r = 0; r < 17; ++r) {
      const float* p = fw + r * 512;
      const float4* p4 = (const float4*)p;
#pragma unroll
      for (int w = 0; w < 4; ++w) {
        float4 f = p4[w];
        sum += f.x; ssq = fmaf(f.x, f.x, ssq); mx = fmaxf(mx, f.x); mn = fminf(mn, f.x);
        sum += f.y; ssq = fmaf(f.y, f.y, ssq); mx = fmaxf(mx, f.y); mn = fminf(mn, f.y);
        sum += f.z; ssq = fmaf(f.z, f.z, ssq); mx = fmaxf(mx, f.z); mn = fminf(mn, f.z);
        sum += f.w; ssq = fmaf(f.w, f.w, ssq); mx = fmaxf(mx, f.w); mn = fminf(mn, f.w);
      }
      float t = p[16];
      sum += t; ssq = fmaf(t, t, ssq); mx = fmaxf(mx, t); mn = fminf(mn, t);
    }
    float mean = sum * (1.0f / 289.0f);
    float var = fmaxf(ssq * (1.0f / 289.0f) - mean * mean, 0.0f);
    float fm = mean / G_MEAN_F;
    float fs = sqrtf(var) / G_STD_F;
    float fmx = (mx - fm) / G_STD_F;
    float fmn = (fm - mn) / G_STD_F;
    if (!valid) { fm = fs = fmx = fmn = h1 = h2 = h3 = h4 = 0.0f; }
    fm = wred(fm); fs = wred(fs); fmx = wred(fmx); fmn = wred(fmn);
    h1 = wred(h1); h2 = wred(h2); h3 = wred(h3); h4 = wred(h4);
    if (lane == 0) {
      const float s = 1.0f / 15376.0f;
      unsafeAtomicAdd(outb + 0, fm * s);
      unsafeAtomicAdd(outb + 1, fs * s);
      unsafeAtomicAdd(outb + 2, fmx * s);
      unsafeAtomicAdd(outb + 3, fmn * s);
      unsafeAtomicAdd(outb + 4, h1 * s);
      unsafeAtomicAdd(outb + 5, h2 * s);
      unsafeAtomicAdd(outb + 6, h3 * s);
      unsafeAtomicAdd(outb + 7, h4 * s);
    }
  } else {
    glcm_dr1_pair(mbase, ly4, valid, outb);
    glcm_one<1, -1>(mbase, ly4, 256.0f, valid, outb, 3, 7);
    glcm_one<4, 0>(mbase, ly4, 221.0f, valid, outb, 10, -1);
    glcm_one<3, -3>(mbase, ly4, 196.0f, valid, outb, 11, -1);
  }
}

extern "C" void kernel_launch(void* const* d_in, const int* in_sizes, int n_in,
                              void* d_out, int out_size, void* d_ws, size_t ws_size,
                              hipStream_t stream)
{
  const float* x = (const float*)d_in[0];
  float* out = (float*)d_out;
  hipMemsetAsync(out, 0, (size_t)out_size * sizeof(float), stream);
  dim3 grid(16, 16, 8);   // x: wy tiles, y: wx tiles, z: batch
  dim3 block(128);
  glcm_feat_kernel<<<grid, block, 0, stream>>>(x, out);
}